// Round 1
// baseline (3533.875 us; speedup 1.0000x reference)
//
#include <hip/hip_runtime.h>
#include <math.h>

// Problem constants (reference: B=8, S=1024, D=1024, H=16, DK=64)
constexpr int B_ = 8, S_ = 1024, D_ = 1024, H_ = 16, DK_ = 64;
constexpr int M_ = B_ * S_;  // 8192 tokens

// ---------------------------------------------------------------------------
// GEMM: Y[m,n] = sum_k X[m,k] * W[n,k] + bias[n]   (i.e. y = x @ W.T + b)
// X: [M,1024] row-major, W: [1024,1024] row-major (nn.Linear weight)
// store_mode 0: out[m*N + n]                         (plain row-major)
// store_mode 1: out[((b*H+h)*S + s)*DK + dk]         (scatter to [B,H,S,DK])
// Tile: 64x64 output per block, K-tile 16, 256 threads, 4x4 micro-tile.
// ---------------------------------------------------------------------------
#define TM 64
#define TN 64
#define TKK 16

__global__ __launch_bounds__(256) void gemm_bt(
    const float* __restrict__ X, const float* __restrict__ W,
    const float* __restrict__ bias, float* __restrict__ out,
    int K, int N, int store_mode)
{
    __shared__ float As[TM][TKK + 1];   // +1 pad: breaks power-of-2 bank stride
    __shared__ float Bs[TN][TKK + 1];

    const int tid = threadIdx.x;
    const int bm = blockIdx.x, bn = blockIdx.y;
    const int tx = tid % 16, ty = tid / 16;

    float acc[4][4] = {};

    const int lr = tid / 4;          // 0..63 load row
    const int lc = (tid % 4) * 4;    // 0,4,8,12 load col chunk
    const float* Xrow = X + (size_t)(bm * TM + lr) * K;
    const float* Wrow = W + (size_t)(bn * TN + lr) * K;

    for (int k0 = 0; k0 < K; k0 += TKK) {
        float4 xa = *(const float4*)(Xrow + k0 + lc);
        float4 wa = *(const float4*)(Wrow + k0 + lc);
        As[lr][lc + 0] = xa.x; As[lr][lc + 1] = xa.y;
        As[lr][lc + 2] = xa.z; As[lr][lc + 3] = xa.w;
        Bs[lr][lc + 0] = wa.x; Bs[lr][lc + 1] = wa.y;
        Bs[lr][lc + 2] = wa.z; Bs[lr][lc + 3] = wa.w;
        __syncthreads();
#pragma unroll
        for (int kk = 0; kk < TKK; ++kk) {
            float a0 = As[ty * 4 + 0][kk], a1 = As[ty * 4 + 1][kk];
            float a2 = As[ty * 4 + 2][kk], a3 = As[ty * 4 + 3][kk];
            float b0 = Bs[tx * 4 + 0][kk], b1 = Bs[tx * 4 + 1][kk];
            float b2 = Bs[tx * 4 + 2][kk], b3 = Bs[tx * 4 + 3][kk];
            acc[0][0] += a0 * b0; acc[0][1] += a0 * b1; acc[0][2] += a0 * b2; acc[0][3] += a0 * b3;
            acc[1][0] += a1 * b0; acc[1][1] += a1 * b1; acc[1][2] += a1 * b2; acc[1][3] += a1 * b3;
            acc[2][0] += a2 * b0; acc[2][1] += a2 * b1; acc[2][2] += a2 * b2; acc[2][3] += a2 * b3;
            acc[3][0] += a3 * b0; acc[3][1] += a3 * b1; acc[3][2] += a3 * b2; acc[3][3] += a3 * b3;
        }
        __syncthreads();
    }

#pragma unroll
    for (int i = 0; i < 4; ++i) {
        const int m = bm * TM + ty * 4 + i;
#pragma unroll
        for (int j = 0; j < 4; ++j) {
            const int n = bn * TN + tx * 4 + j;
            const float val = acc[i][j] + bias[n];
            if (store_mode == 0) {
                out[(size_t)m * N + n] = val;
            } else {
                const int b = m / S_, s = m % S_;
                const int h = n / DK_, dk = n % DK_;
                out[(((size_t)(b * H_ + h)) * S_ + s) * DK_ + dk] = val;
            }
        }
    }
}

// ---------------------------------------------------------------------------
// Flash-style attention. One block per (b, h, 64-row q-tile). fp32.
// Q,K,V in [B,H,S,DK] layout (so each 64x64 tile is contiguous 16 KB).
// mask: [B,1,S,S] int32; mask==0 -> score = -1e9 (applied after 1/8 scale,
// matching the reference order).
// Output: attn_out [B,S,D] row-major (D index = h*DK + dk).
// ---------------------------------------------------------------------------
__global__ __launch_bounds__(256) void attn_fwd(
    const float* __restrict__ Q, const float* __restrict__ Kt,
    const float* __restrict__ Vt, const int* __restrict__ mask,
    float* __restrict__ out)
{
    constexpr int TQ = 64, TK = 64;
    __shared__ float Qs[TQ][DK_ + 1];
    __shared__ float Ks[TK][DK_ + 1];
    __shared__ float Vs[TK][DK_ + 1];
    __shared__ float Sc[TQ][TK + 1];
    __shared__ float alpha_s[TQ];
    __shared__ float l_s[TQ];

    const int tid = threadIdx.x;
    constexpr int NQT = S_ / TQ;  // 16
    const int qt = blockIdx.x % NQT;
    const int h  = (blockIdx.x / NQT) % H_;
    const int b  = blockIdx.x / (NQT * H_);

    const float* Qbase = Q  + ((size_t)(b * H_ + h) * S_ + qt * TQ) * DK_;
    const float* Kb    = Kt + (size_t)(b * H_ + h) * S_ * DK_;
    const float* Vb    = Vt + (size_t)(b * H_ + h) * S_ * DK_;
    const int*   mbase = mask + ((size_t)b * S_ + qt * TQ) * S_;

    // Load Q tile (contiguous 4096 floats)
#pragma unroll
    for (int i = 0; i < 4; ++i) {
        const int fi = (tid + i * 256) * 4;
        const float4 v4 = *(const float4*)(Qbase + fi);
        const int r = fi / DK_, c = fi % DK_;
        Qs[r][c] = v4.x; Qs[r][c + 1] = v4.y; Qs[r][c + 2] = v4.z; Qs[r][c + 3] = v4.w;
    }

    const int kcol = tid % 64;   // dk / key-column lane
    const int qg   = tid / 64;   // 0..3: owns q rows qg*16 .. qg*16+15

    float Oacc[16];
#pragma unroll
    for (int i = 0; i < 16; ++i) Oacc[i] = 0.f;
    float mrow = -INFINITY, lrow = 0.f;  // live in threads tid<64 (row owners)

    for (int ktile = 0; ktile < S_ / TK; ++ktile) {
        __syncthreads();  // protect Ks/Vs/Sc from previous iteration readers
        const float* Kg = Kb + (size_t)ktile * TK * DK_;
        const float* Vg = Vb + (size_t)ktile * TK * DK_;
#pragma unroll
        for (int i = 0; i < 4; ++i) {
            const int fi = (tid + i * 256) * 4;
            const int r = fi / DK_, c = fi % DK_;
            const float4 kv = *(const float4*)(Kg + fi);
            Ks[r][c] = kv.x; Ks[r][c + 1] = kv.y; Ks[r][c + 2] = kv.z; Ks[r][c + 3] = kv.w;
            const float4 vv = *(const float4*)(Vg + fi);
            Vs[r][c] = vv.x; Vs[r][c + 1] = vv.y; Vs[r][c + 2] = vv.z; Vs[r][c + 3] = vv.w;
        }
        __syncthreads();

        // Scores: thread (qg,kcol) computes 16 rows x 1 key column
#pragma unroll 4
        for (int i = 0; i < 16; ++i) {
            const int qr = qg * 16 + i;
            float s = 0.f;
#pragma unroll
            for (int d = 0; d < DK_; ++d) s += Qs[qr][d] * Ks[kcol][d];
            s *= 0.125f;  // 1/sqrt(64)
            const int mv = mbase[(size_t)qr * S_ + ktile * TK + kcol];
            if (mv == 0) s = -1e9f;
            Sc[qr][kcol] = s;
        }
        __syncthreads();

        // Online softmax row update (one row owner per thread, tid<64)
        if (tid < TQ) {
            float rowmax = -INFINITY;
#pragma unroll
            for (int k = 0; k < TK; ++k) rowmax = fmaxf(rowmax, Sc[tid][k]);
            const float newm = fmaxf(mrow, rowmax);
            const float al = __expf(mrow - newm);
            float psum = 0.f;
#pragma unroll
            for (int k = 0; k < TK; ++k) {
                const float p = __expf(Sc[tid][k] - newm);
                Sc[tid][k] = p;
                psum += p;
            }
            lrow = lrow * al + psum;
            mrow = newm;
            alpha_s[tid] = al;
        }
        __syncthreads();

        // O update: O[qr][kcol] = O*alpha + P~ @ V
#pragma unroll 4
        for (int i = 0; i < 16; ++i) {
            const int qr = qg * 16 + i;
            const float a = alpha_s[qr];
            float sum = 0.f;
#pragma unroll
            for (int k = 0; k < TK; ++k) sum += Sc[qr][k] * Vs[k][kcol];
            Oacc[i] = Oacc[i] * a + sum;
        }
    }

    if (tid < TQ) l_s[tid] = lrow;
    __syncthreads();

#pragma unroll
    for (int i = 0; i < 16; ++i) {
        const int qr = qg * 16 + i;
        const float val = Oacc[i] / l_s[qr];
        // attn_out[b, s=qt*TQ+qr, h*DK + kcol]
        out[((size_t)b * S_ + qt * TQ + qr) * D_ + h * DK_ + kcol] = val;
    }
}

// ---------------------------------------------------------------------------
extern "C" void kernel_launch(void* const* d_in, const int* in_sizes, int n_in,
                              void* d_out, int out_size, void* d_ws, size_t ws_size,
                              hipStream_t stream) {
    const float* q    = (const float*)d_in[0];
    const float* k    = (const float*)d_in[1];
    const float* v    = (const float*)d_in[2];
    const int*   mask = (const int*)d_in[3];
    const float* WQw  = (const float*)d_in[4];
    const float* WQb  = (const float*)d_in[5];
    const float* WKw  = (const float*)d_in[6];
    const float* WKb  = (const float*)d_in[7];
    const float* WVw  = (const float*)d_in[8];
    const float* WVb  = (const float*)d_in[9];
    const float* WOw  = (const float*)d_in[10];
    const float* WOb  = (const float*)d_in[11];
    float* out = (float*)d_out;

    float* ws = (float*)d_ws;
    const size_t per = (size_t)B_ * H_ * S_ * DK_;  // 8388608 floats
    float* Qp = ws;
    float* Kp = ws + per;
    float* Vp = ws + 2 * per;
    float* AO = ws + 3 * per;  // attention output [B,S,D]

    dim3 grid(M_ / TM, D_ / TN);  // 128 x 16
    // Q/K/V projections -> [B,H,S,DK]
    gemm_bt<<<grid, 256, 0, stream>>>(q, WQw, WQb, Qp, D_, D_, 1);
    gemm_bt<<<grid, 256, 0, stream>>>(k, WKw, WKb, Kp, D_, D_, 1);
    gemm_bt<<<grid, 256, 0, stream>>>(v, WVw, WVb, Vp, D_, D_, 1);
    // Attention -> AO [B,S,D]
    attn_fwd<<<dim3(B_ * H_ * (S_ / 64)), 256, 0, stream>>>(Qp, Kp, Vp, mask, AO);
    // Output projection -> d_out [B,S,D]
    gemm_bt<<<grid, 256, 0, stream>>>(AO, WOw, WOb, out, D_, D_, 0);
}

// Round 2
// 529.582 us; speedup vs baseline: 6.6729x; 6.6729x over previous
//
#include <hip/hip_runtime.h>
#include <math.h>

typedef __bf16 bf16;
typedef __bf16 bf16x8 __attribute__((ext_vector_type(8)));
typedef __bf16 bf16x4 __attribute__((ext_vector_type(4)));
typedef float f32x4 __attribute__((ext_vector_type(4)));

constexpr int B_ = 8, S_ = 1024, D_ = 1024, H_ = 16, DK_ = 64;
constexpr int M_ = B_ * S_;  // 8192

// ---------------------------------------------------------------------------
// fp32 -> bf16 elementwise convert (RNE via native cast), 4 elems/thread
// ---------------------------------------------------------------------------
__global__ __launch_bounds__(256) void cvt_bf16(
    const float* __restrict__ in, bf16* __restrict__ out, int n)
{
    int i = (blockIdx.x * 256 + threadIdx.x) * 4;
    if (i + 3 >= n + 3) return;   // n is a multiple of 4; simple guard
    if (i >= n) return;
    float4 v = *(const float4*)(in + i);
    bf16x4 o = { (bf16)v.x, (bf16)v.y, (bf16)v.z, (bf16)v.w };
    *(bf16x4*)(out + i) = o;
}

// ---------------------------------------------------------------------------
// bf16 MFMA GEMM: C[m,n] = sum_k X[m,k]*W[n,k] + bias[n]   (y = x @ W.T + b)
// X:[M,1024] bf16 row-major, W:[1024,1024] bf16 row-major. K = 1024.
// Tile 128x128, BK=32, 256 thr = 4 waves in 2x2, per-wave 4x4 frags of
// 16x16x32 MFMA. Verified layouts (learn_hip m89/m91):
//   A frag: lane holds A[m = lane&15][k = (lane>>4)*8 + j], j=0..7
//   B frag: lane holds B[k = (lane>>4)*8 + j][n = lane&15]  (= W row n, contig k)
//   C/D   : col = lane&15, row = (lane>>4)*4 + reg
// OUT_MODE 0: fp32 row-major [M,1024]
// OUT_MODE 1: bf16 scatter to [B,H,S,DK]
// ---------------------------------------------------------------------------
#define LDA 40   // LDS row stride (elems): 80B rows, 16B-aligned, spreads banks

template<int OUT_MODE>
__global__ __launch_bounds__(256) void gemm_mfma(
    const bf16* __restrict__ X, const bf16* __restrict__ W,
    const float* __restrict__ bias, void* __restrict__ outv)
{
    constexpr int K = 1024;
    __shared__ bf16 As[128 * LDA];
    __shared__ bf16 Bs[128 * LDA];

    const int tid  = threadIdx.x;
    const int lane = tid & 63;
    const int w    = tid >> 6;
    const int wm   = w & 1, wn = w >> 1;        // 2x2 wave grid (64x64 each)
    const int quad = lane >> 4, l15 = lane & 15;
    const int bm = blockIdx.x * 128, bn = blockIdx.y * 128;

    f32x4 acc[4][4];
#pragma unroll
    for (int i = 0; i < 4; ++i)
#pragma unroll
        for (int j = 0; j < 4; ++j)
#pragma unroll
            for (int r = 0; r < 4; ++r) acc[i][j][r] = 0.f;

    // staging: thread t covers rows r0 and r0+64, 8 bf16 (16B) each
    const int r0 = tid >> 2;            // 0..63
    const int c0 = (tid & 3) * 8;       // 0,8,16,24
    const bf16* Xp = X + (size_t)(bm + r0) * K + c0;
    const bf16* Wp = W + (size_t)(bn + r0) * K + c0;
    bf16* As0 = As + r0 * LDA + c0;
    bf16* Bs0 = Bs + r0 * LDA + c0;

    for (int k0 = 0; k0 < K; k0 += 32) {
        __syncthreads();
        *(bf16x8*)(As0)            = *(const bf16x8*)(Xp + k0);
        *(bf16x8*)(As0 + 64 * LDA) = *(const bf16x8*)(Xp + (size_t)64 * K + k0);
        *(bf16x8*)(Bs0)            = *(const bf16x8*)(Wp + k0);
        *(bf16x8*)(Bs0 + 64 * LDA) = *(const bf16x8*)(Wp + (size_t)64 * K + k0);
        __syncthreads();

        bf16x8 a[4], b[4];
#pragma unroll
        for (int i = 0; i < 4; ++i)
            a[i] = *(const bf16x8*)(As + (wm * 64 + i * 16 + l15) * LDA + quad * 8);
#pragma unroll
        for (int j = 0; j < 4; ++j)
            b[j] = *(const bf16x8*)(Bs + (wn * 64 + j * 16 + l15) * LDA + quad * 8);
#pragma unroll
        for (int i = 0; i < 4; ++i)
#pragma unroll
            for (int j = 0; j < 4; ++j)
                acc[i][j] = __builtin_amdgcn_mfma_f32_16x16x32_bf16(
                    a[i], b[j], acc[i][j], 0, 0, 0);
    }

#pragma unroll
    for (int i = 0; i < 4; ++i) {
#pragma unroll
        for (int j = 0; j < 4; ++j) {
            const int n = bn + wn * 64 + j * 16 + l15;
            const float bs = bias[n];
#pragma unroll
            for (int r = 0; r < 4; ++r) {
                const int m = bm + wm * 64 + i * 16 + quad * 4 + r;
                const float val = acc[i][j][r] + bs;
                if (OUT_MODE == 0) {
                    ((float*)outv)[(size_t)m * 1024 + n] = val;
                } else {
                    const int bb = m >> 10, s = m & 1023;
                    const int h = n >> 6, dk = n & 63;
                    ((bf16*)outv)[(((size_t)(bb * 16 + h)) * 1024 + s) * 64 + dk] = (bf16)val;
                }
            }
        }
    }
}

// ---------------------------------------------------------------------------
// MFMA flash attention. One block per (b, h, 64-q-tile). 256 thr = 4 waves,
// wave w owns q-rows w*16..w*16+15 of the tile. K/V tiles of 64.
// Q,K,V in [B,H,S,DK] bf16. Softmax state per lane: rows quad*4+r (matches
// C-frag row mapping). P: fp32 C-frags -> bf16 via LDS (m120 round-trip).
// V staged TRANSPOSED (Vs[d][kk]) so PV B-frags are contiguous ds_read_b128.
// out: bf16 [B,S,D] (feeds the bf16 O-projection GEMM).
// ---------------------------------------------------------------------------
#define LDT 72   // attn LDS row stride (144B rows, 16B-aligned, 2-lanes/bank)

__global__ __launch_bounds__(256) void attn_mfma(
    const bf16* __restrict__ Q, const bf16* __restrict__ Kt,
    const bf16* __restrict__ Vt, const int* __restrict__ mask,
    bf16* __restrict__ out)
{
    __shared__ bf16 Qs[64 * LDT];
    __shared__ bf16 Ks[64 * LDT];
    __shared__ bf16 Vs[64 * LDT];   // transposed: Vs[d][kk]
    __shared__ bf16 Ps[64 * LDT];   // P rows (wave-private row ranges)

    const int tid  = threadIdx.x;
    const int lane = tid & 63;
    const int w    = tid >> 6;
    const int quad = lane >> 4, l15 = lane & 15;

    constexpr int NQT = S_ / 64;  // 16
    const int qt = blockIdx.x % NQT;
    const int h  = (blockIdx.x / NQT) % H_;
    const int b  = blockIdx.x / (NQT * H_);

    const bf16* Qg = Q  + ((size_t)(b * H_ + h) * S_ + qt * 64) * DK_;
    const bf16* Kg = Kt + (size_t)(b * H_ + h) * S_ * DK_;
    const bf16* Vg = Vt + (size_t)(b * H_ + h) * S_ * DK_;
    // lane's 4 q-rows: qt*64 + w*16 + quad*4 + r
    const int* mbase = mask + ((size_t)b * S_ + qt * 64 + w * 16 + quad * 4) * S_;

    // stage Q tile (64x64): thread covers rows rr, rr+32; 8 bf16 each
    const int rr = tid >> 3;            // 0..31
    const int cc = (tid & 7) * 8;       // 0..56
    *(bf16x8*)(Qs + rr * LDT + cc)        = *(const bf16x8*)(Qg + rr * 64 + cc);
    *(bf16x8*)(Qs + (rr + 32) * LDT + cc) = *(const bf16x8*)(Qg + (rr + 32) * 64 + cc);
    __syncthreads();

    // Q A-frags (constant across k-tiles): row = w*16 + l15, k = t*32 + quad*8
    bf16x8 qa[2];
#pragma unroll
    for (int t = 0; t < 2; ++t)
        qa[t] = *(const bf16x8*)(Qs + (w * 16 + l15) * LDT + t * 32 + quad * 8);

    f32x4 O[4];
#pragma unroll
    for (int dj = 0; dj < 4; ++dj)
#pragma unroll
        for (int r = 0; r < 4; ++r) O[dj][r] = 0.f;
    float mrow[4] = { -INFINITY, -INFINITY, -INFINITY, -INFINITY };
    float lrow[4] = { 0.f, 0.f, 0.f, 0.f };

    for (int kt = 0; kt < S_ / 64; ++kt) {
        __syncthreads();  // prior iteration's PV reads of Ks/Vs done
        // stage K tile (natural) and V tile (transposed)
        *(bf16x8*)(Ks + rr * LDT + cc) =
            *(const bf16x8*)(Kg + kt * 4096 + rr * 64 + cc);
        *(bf16x8*)(Ks + (rr + 32) * LDT + cc) =
            *(const bf16x8*)(Kg + kt * 4096 + (rr + 32) * 64 + cc);
        {
            bf16x8 v0 = *(const bf16x8*)(Vg + kt * 4096 + rr * 64 + cc);
            bf16x8 v1 = *(const bf16x8*)(Vg + kt * 4096 + (rr + 32) * 64 + cc);
#pragma unroll
            for (int d = 0; d < 8; ++d) {
                Vs[(cc + d) * LDT + rr]      = v0[d];
                Vs[(cc + d) * LDT + rr + 32] = v1[d];
            }
        }
        __syncthreads();

        // ---- S = Q K^T (wave's 16 rows x 64 cols), 8 MFMAs ----
        f32x4 sf[4];
#pragma unroll
        for (int j = 0; j < 4; ++j)
#pragma unroll
            for (int r = 0; r < 4; ++r) sf[j][r] = 0.f;
#pragma unroll
        for (int t = 0; t < 2; ++t) {
#pragma unroll
            for (int j = 0; j < 4; ++j) {
                bf16x8 kb = *(const bf16x8*)(Ks + (j * 16 + l15) * LDT + t * 32 + quad * 8);
                sf[j] = __builtin_amdgcn_mfma_f32_16x16x32_bf16(qa[t], kb, sf[j], 0, 0, 0);
            }
        }

        // ---- scale + mask + tile row-max ----
        float tmax[4] = { -INFINITY, -INFINITY, -INFINITY, -INFINITY };
#pragma unroll
        for (int j = 0; j < 4; ++j) {
#pragma unroll
            for (int r = 0; r < 4; ++r) {
                float s = sf[j][r] * 0.125f;
                const int mv = mbase[(size_t)r * S_ + kt * 64 + j * 16 + l15];
                s = (mv == 0) ? -1e9f : s;
                sf[j][r] = s;
                tmax[r] = fmaxf(tmax[r], s);
            }
        }
#pragma unroll
        for (int off = 1; off < 16; off <<= 1)
#pragma unroll
            for (int r = 0; r < 4; ++r)
                tmax[r] = fmaxf(tmax[r], __shfl_xor(tmax[r], off));

        // ---- online softmax update ----
        float alpha[4], psum[4];
#pragma unroll
        for (int r = 0; r < 4; ++r) {
            const float mn = fmaxf(mrow[r], tmax[r]);
            alpha[r] = __expf(mrow[r] - mn);   // exp(-inf - finite) = 0 on first tile
            mrow[r] = mn;
            psum[r] = 0.f;
        }
#pragma unroll
        for (int j = 0; j < 4; ++j) {
#pragma unroll
            for (int r = 0; r < 4; ++r) {
                const float p = __expf(sf[j][r] - mrow[r]);
                const bf16 pb = (bf16)p;
                Ps[(w * 16 + quad * 4 + r) * LDT + j * 16 + l15] = pb;
                psum[r] += (float)pb;   // use rounded p: O and l stay consistent
            }
        }
#pragma unroll
        for (int off = 1; off < 16; off <<= 1)
#pragma unroll
            for (int r = 0; r < 4; ++r)
                psum[r] += __shfl_xor(psum[r], off);
#pragma unroll
        for (int r = 0; r < 4; ++r) lrow[r] = lrow[r] * alpha[r] + psum[r];

        // rescale O by alpha (rows = quad*4+r, matches frag regs)
#pragma unroll
        for (int dj = 0; dj < 4; ++dj)
#pragma unroll
            for (int r = 0; r < 4; ++r) O[dj][r] *= alpha[r];

        // ---- O += P V (8 MFMAs). Same-wave LDS write->read is in-order. ----
#pragma unroll
        for (int t = 0; t < 2; ++t) {
            bf16x8 pa = *(const bf16x8*)(Ps + (w * 16 + l15) * LDT + t * 32 + quad * 8);
#pragma unroll
            for (int dj = 0; dj < 4; ++dj) {
                bf16x8 vb = *(const bf16x8*)(Vs + (dj * 16 + l15) * LDT + t * 32 + quad * 8);
                O[dj] = __builtin_amdgcn_mfma_f32_16x16x32_bf16(pa, vb, O[dj], 0, 0, 0);
            }
        }
    }

    // epilogue: out[b, qt*64 + w*16 + quad*4 + r, h*64 + dj*16 + l15]
#pragma unroll
    for (int dj = 0; dj < 4; ++dj) {
#pragma unroll
        for (int r = 0; r < 4; ++r) {
            const float val = O[dj][r] / lrow[r];
            out[((size_t)b * S_ + qt * 64 + w * 16 + quad * 4 + r) * D_
                + h * DK_ + dj * 16 + l15] = (bf16)val;
        }
    }
}

// ---------------------------------------------------------------------------
extern "C" void kernel_launch(void* const* d_in, const int* in_sizes, int n_in,
                              void* d_out, int out_size, void* d_ws, size_t ws_size,
                              hipStream_t stream) {
    const float* q    = (const float*)d_in[0];
    const float* k    = (const float*)d_in[1];
    const float* v    = (const float*)d_in[2];
    const int*   mask = (const int*)d_in[3];
    const float* WQw  = (const float*)d_in[4];
    const float* WQb  = (const float*)d_in[5];
    const float* WKw  = (const float*)d_in[6];
    const float* WKb  = (const float*)d_in[7];
    const float* WVw  = (const float*)d_in[8];
    const float* WVb  = (const float*)d_in[9];
    const float* WOw  = (const float*)d_in[10];
    const float* WOb  = (const float*)d_in[11];

    bf16* ws = (bf16*)d_ws;
    const size_t A8 = (size_t)M_ * D_;   // 8388608
    const size_t W1 = (size_t)D_ * D_;   // 1048576
    bf16* qb  = ws;
    bf16* kb  = qb  + A8;
    bf16* vb  = kb  + A8;
    bf16* wqb = vb  + A8;
    bf16* wkb = wqb + W1;
    bf16* wvb = wkb + W1;
    bf16* wob = wvb + W1;
    bf16* Qp  = wob + W1;   // [B,H,S,DK]
    bf16* Kp  = Qp + A8;
    bf16* Vp  = Kp + A8;
    bf16* AO  = Vp + A8;    // [B,S,D]

    // fp32 -> bf16 conversions
    cvt_bf16<<<dim3(A8 / 1024), 256, 0, stream>>>(q, qb, (int)A8);
    cvt_bf16<<<dim3(A8 / 1024), 256, 0, stream>>>(k, kb, (int)A8);
    cvt_bf16<<<dim3(A8 / 1024), 256, 0, stream>>>(v, vb, (int)A8);
    cvt_bf16<<<dim3(W1 / 1024), 256, 0, stream>>>(WQw, wqb, (int)W1);
    cvt_bf16<<<dim3(W1 / 1024), 256, 0, stream>>>(WKw, wkb, (int)W1);
    cvt_bf16<<<dim3(W1 / 1024), 256, 0, stream>>>(WVw, wvb, (int)W1);
    cvt_bf16<<<dim3(W1 / 1024), 256, 0, stream>>>(WOw, wob, (int)W1);

    dim3 gg(M_ / 128, D_ / 128);  // 64 x 8
    gemm_mfma<1><<<gg, 256, 0, stream>>>(qb, wqb, WQb, (void*)Qp);
    gemm_mfma<1><<<gg, 256, 0, stream>>>(kb, wkb, WKb, (void*)Kp);
    gemm_mfma<1><<<gg, 256, 0, stream>>>(vb, wvb, WVb, (void*)Vp);

    attn_mfma<<<dim3(B_ * H_ * (S_ / 64)), 256, 0, stream>>>(Qp, Kp, Vp, mask, AO);

    gemm_mfma<0><<<gg, 256, 0, stream>>>(AO, wob, WOb, d_out);
}

// Round 4
// 383.789 us; speedup vs baseline: 9.2078x; 1.3799x over previous
//
#include <hip/hip_runtime.h>
#include <math.h>

typedef __bf16 bf16;
typedef __bf16 bf16x8 __attribute__((ext_vector_type(8)));
typedef __bf16 bf16x4 __attribute__((ext_vector_type(4)));
typedef float f32x4 __attribute__((ext_vector_type(4)));

constexpr int B_ = 8, S_ = 1024, D_ = 1024, H_ = 16, DK_ = 64;
constexpr int M_ = B_ * S_;                 // 8192
constexpr size_t A8 = (size_t)1 << 23;      // M_*D_ = 8388608
constexpr size_t W1 = (size_t)1 << 20;      // D_*D_ = 1048576
constexpr float QSCALE = 0.18033688011112042f;  // 0.125 * log2(e)

#if __has_builtin(__builtin_amdgcn_exp2f)
#define EXP2F(x) __builtin_amdgcn_exp2f(x)
#else
#define EXP2F(x) exp2f(x)
#endif
#if __has_builtin(__builtin_amdgcn_rcpf)
#define RCPF(x) __builtin_amdgcn_rcpf(x)
#else
#define RCPF(x) (1.0f / (x))
#endif

#define GAS(p) ((const __attribute__((address_space(1))) void*)(p))
#define LAS(p) ((__attribute__((address_space(3))) void*)(p))

// DPP row-rotate reduction helpers (16-lane rows; VALU pipe, no LDS traffic)
template<int CTRL>
__device__ __forceinline__ float row_ror(float v) {
    int i = __builtin_bit_cast(int, v);
    i = __builtin_amdgcn_update_dpp(i, i, CTRL, 0xF, 0xF, false);
    return __builtin_bit_cast(float, i);
}
__device__ __forceinline__ float rowmax16(float v) {
    v = fmaxf(v, row_ror<0x121>(v));
    v = fmaxf(v, row_ror<0x122>(v));
    v = fmaxf(v, row_ror<0x124>(v));
    v = fmaxf(v, row_ror<0x128>(v));
    return v;
}
__device__ __forceinline__ float rowsum16(float v) {
    v += row_ror<0x121>(v);
    v += row_ror<0x122>(v);
    v += row_ror<0x124>(v);
    v += row_ror<0x128>(v);
    return v;
}

// ---------------------------------------------------------------------------
// Fused fp32->bf16 convert for q,k,v (A8 each) + 4 weight matrices (W1 each).
// ---------------------------------------------------------------------------
__global__ __launch_bounds__(256) void cvt_all(
    const float* __restrict__ q, const float* __restrict__ k,
    const float* __restrict__ v, const float* __restrict__ w0,
    const float* __restrict__ w1, const float* __restrict__ w2,
    const float* __restrict__ w3, bf16* __restrict__ dst)
{
    size_t e = ((size_t)blockIdx.x * 256 + threadIdx.x) * 8;
    const float* src;
    size_t off;
    if (e < 3 * A8) {
        int t = (int)(e >> 23);
        src = (t == 0) ? q : (t == 1) ? k : v;
        off = e & (A8 - 1);
    } else {
        size_t ew = e - 3 * A8;
        int t = (int)(ew >> 20);
        src = (t == 0) ? w0 : (t == 1) ? w1 : (t == 2) ? w2 : w3;
        off = ew & (W1 - 1);
    }
    float4 a = *(const float4*)(src + off);
    float4 b = *(const float4*)(src + off + 4);
    bf16x8 o = { (bf16)a.x, (bf16)a.y, (bf16)a.z, (bf16)a.w,
                 (bf16)b.x, (bf16)b.y, (bf16)b.z, (bf16)b.w };
    *(bf16x8*)(dst + e) = o;
}

// ---------------------------------------------------------------------------
// Mask -> additive bf16, pre-permuted into MFMA frag order:
// tile (b,qt,kt) 64x64; within tile [w][lane][e=j*4+r]; 0 or -1e9.
// ---------------------------------------------------------------------------
__global__ __launch_bounds__(256) void mask_cvt(
    const int* __restrict__ mask, bf16* __restrict__ mp)
{
    const int bx = blockIdx.x;
    const int kt = bx & 15, qt = (bx >> 4) & 15, b = bx >> 8;
    const int tid = threadIdx.x;
    const int w = tid >> 6, lane = tid & 63;
    const int quad = lane >> 4, l15 = lane & 15;

    const int* src = mask + ((size_t)b << 20)
                   + (size_t)(qt * 64 + w * 16 + quad * 4) * 1024
                   + kt * 64 + l15;
    bf16 vals[16];
#pragma unroll
    for (int j = 0; j < 4; ++j)
#pragma unroll
        for (int r = 0; r < 4; ++r) {
            int m = src[(size_t)r * 1024 + j * 16];
            vals[j * 4 + r] = m ? (bf16)0.0f : (bf16)(-1e9f);
        }
    bf16* dst = mp + (((size_t)(b * 16 + qt) * 16 + kt) << 12) + (w * 64 + lane) * 16;
    bf16x8 o0 = { vals[0], vals[1], vals[2],  vals[3],  vals[4],  vals[5],  vals[6],  vals[7]  };
    bf16x8 o1 = { vals[8], vals[9], vals[10], vals[11], vals[12], vals[13], vals[14], vals[15] };
    *(bf16x8*)dst = o0;
    *(bf16x8*)(dst + 8) = o1;
}

// ---------------------------------------------------------------------------
// bf16 MFMA GEMM (m97 recipe): C = X @ W^T + bias. 128x128 tile, BK=32,
// global_load_lds width=16 into UNPADDED LDS.
// OUT_MODE 0: fp32 [M,1024];  1: bf16 scatter [B,H,S,DK] (scaled by oscale);
// 2: bf16 scatter [B,H,DK,S] (transposed V), packed bf16x4 stores.
// ---------------------------------------------------------------------------
template<int OUT_MODE>
__global__ __launch_bounds__(256) void gemm_mfma(
    const bf16* __restrict__ X, const bf16* __restrict__ W,
    const float* __restrict__ bias, void* __restrict__ outv, float oscale)
{
    constexpr int K = 1024;
    __shared__ bf16 As[128 * 32];
    __shared__ bf16 Bs[128 * 32];

    const int tid  = threadIdx.x;
    const int lane = tid & 63;
    const int w    = tid >> 6;
    const int wm   = w & 1, wn = w >> 1;
    const int quad = lane >> 4, l15 = lane & 15;
    const int bm = blockIdx.x * 128, bn = blockIdx.y * 128;

    f32x4 acc[4][4];
#pragma unroll
    for (int i = 0; i < 4; ++i)
#pragma unroll
        for (int j = 0; j < 4; ++j)
#pragma unroll
            for (int r = 0; r < 4; ++r) acc[i][j][r] = 0.f;

    const int lrow = lane >> 2;          // 0..15
    const int lcol = (lane & 3) * 8;     // 0,8,16,24 (elems)

    for (int k0 = 0; k0 < K; k0 += 32) {
        __syncthreads();
#pragma unroll
        for (int i = 0; i < 2; ++i) {
            const int rbase = w * 16 + i * 64;
            __builtin_amdgcn_global_load_lds(
                GAS(X + (size_t)(bm + rbase + lrow) * K + k0 + lcol),
                LAS(As + rbase * 32), 16, 0, 0);
            __builtin_amdgcn_global_load_lds(
                GAS(W + (size_t)(bn + rbase + lrow) * K + k0 + lcol),
                LAS(Bs + rbase * 32), 16, 0, 0);
        }
        __syncthreads();

        bf16x8 a[4], b[4];
#pragma unroll
        for (int i = 0; i < 4; ++i)
            a[i] = *(const bf16x8*)(As + (wm * 64 + i * 16 + l15) * 32 + quad * 8);
#pragma unroll
        for (int j = 0; j < 4; ++j)
            b[j] = *(const bf16x8*)(Bs + (wn * 64 + j * 16 + l15) * 32 + quad * 8);
#pragma unroll
        for (int i = 0; i < 4; ++i)
#pragma unroll
            for (int j = 0; j < 4; ++j)
                acc[i][j] = __builtin_amdgcn_mfma_f32_16x16x32_bf16(
                    a[i], b[j], acc[i][j], 0, 0, 0);
    }

#pragma unroll
    for (int i = 0; i < 4; ++i) {
#pragma unroll
        for (int j = 0; j < 4; ++j) {
            const int n = bn + wn * 64 + j * 16 + l15;
            const float bs = bias[n];
            if (OUT_MODE == 2) {
                const int m0 = bm + wm * 64 + i * 16 + quad * 4;
                const int bb = m0 >> 10, s0 = m0 & 1023;
                const int h = n >> 6, dk = n & 63;
                bf16x4 o;
#pragma unroll
                for (int r = 0; r < 4; ++r) o[r] = (bf16)(acc[i][j][r] + bs);
                *(bf16x4*)((bf16*)outv + (((size_t)(bb * 16 + h) * 64 + dk) << 10) + s0) = o;
            } else {
#pragma unroll
                for (int r = 0; r < 4; ++r) {
                    const int m = bm + wm * 64 + i * 16 + quad * 4 + r;
                    const float val = acc[i][j][r] + bs;
                    if (OUT_MODE == 0) {
                        ((float*)outv)[(size_t)m * 1024 + n] = val;
                    } else {
                        const int bb = m >> 10, s = m & 1023;
                        const int h = n >> 6, dk = n & 63;
                        ((bf16*)outv)[(((size_t)(bb * 16 + h)) * 1024 + s) * 64 + dk] =
                            (bf16)(val * oscale);
                    }
                }
            }
        }
    }
}

// ---------------------------------------------------------------------------
// MFMA flash attention (exp2 domain; Q pre-scaled by 0.125*log2e).
// Q,K: [B,H,S,DK]; V: [B,H,DK,S] pre-transposed; maskp: permuted additive.
// Ps XOR-swizzled, stride LDP=64 (cols 0..63 — LDP=48 in round 3 was the
// corruption bug: swizzled col indices overflowed into the next row).
// ---------------------------------------------------------------------------
#define LDT 72
#define LDP 64

__global__ __launch_bounds__(256) void attn_mfma(
    const bf16* __restrict__ Q, const bf16* __restrict__ Kt,
    const bf16* __restrict__ Vt, const bf16* __restrict__ maskp,
    bf16* __restrict__ out)
{
    __shared__ bf16 smem[3 * 64 * LDT];
    bf16* Qs = smem;
    bf16* Ks = smem + 64 * LDT;
    bf16* Vs = smem + 2 * 64 * LDT;
    bf16* Ps = smem;                      // aliases Qs (dead after frag load)

    const int tid  = threadIdx.x;
    const int lane = tid & 63;
    const int w    = tid >> 6;
    const int quad = lane >> 4, l15 = lane & 15;

    const int qt = blockIdx.x & 15;
    const int h  = (blockIdx.x >> 4) & 15;
    const int b  = blockIdx.x >> 8;

    const bf16* Qg  = Q  + ((size_t)(b * H_ + h) * S_ + qt * 64) * DK_;
    const bf16* Kg  = Kt + (size_t)(b * H_ + h) * S_ * DK_;
    const bf16* Vgt = Vt + ((size_t)(b * H_ + h) << 16);
    const bf16* mtb = maskp + (((size_t)(b * 16 + qt) * 16) << 12) + (w * 64 + lane) * 16;

    const int rr = tid >> 3;            // 0..31
    const int cc = (tid & 7) * 8;       // 0..56
    *(bf16x8*)(Qs + rr * LDT + cc)        = *(const bf16x8*)(Qg + rr * 64 + cc);
    *(bf16x8*)(Qs + (rr + 32) * LDT + cc) = *(const bf16x8*)(Qg + (rr + 32) * 64 + cc);
    __syncthreads();

    bf16x8 qa[2];
#pragma unroll
    for (int t = 0; t < 2; ++t)
        qa[t] = *(const bf16x8*)(Qs + (w * 16 + l15) * LDT + t * 32 + quad * 8);

    f32x4 O[4];
#pragma unroll
    for (int dj = 0; dj < 4; ++dj)
#pragma unroll
        for (int r = 0; r < 4; ++r) O[dj][r] = 0.f;
    float mrow[4] = { -INFINITY, -INFINITY, -INFINITY, -INFINITY };
    float lrow[4] = { 0.f, 0.f, 0.f, 0.f };

    const int pswz = quad << 4;                       // write-side XOR key
    const int rswz = (l15 >> 2) << 4;                 // read-side XOR key
    bf16* PsW = Ps + (w * 16 + quad * 4) * LDP;
    const bf16* PsR = Ps + (w * 16 + l15) * LDP;

    for (int kt = 0; kt < 16; ++kt) {
        __syncthreads();
        bf16x8 k0 = *(const bf16x8*)(Kg + kt * 4096 + rr * 64 + cc);
        bf16x8 k1 = *(const bf16x8*)(Kg + kt * 4096 + (rr + 32) * 64 + cc);
        bf16x8 v0 = *(const bf16x8*)(Vgt + (size_t)rr * 1024 + kt * 64 + cc);
        bf16x8 v1 = *(const bf16x8*)(Vgt + (size_t)(rr + 32) * 1024 + kt * 64 + cc);
        bf16x8 mv0 = *(const bf16x8*)(mtb + ((size_t)kt << 12));
        bf16x8 mv1 = *(const bf16x8*)(mtb + ((size_t)kt << 12) + 8);
        *(bf16x8*)(Ks + rr * LDT + cc)        = k0;
        *(bf16x8*)(Ks + (rr + 32) * LDT + cc) = k1;
        *(bf16x8*)(Vs + rr * LDT + cc)        = v0;   // Vs[d][kk]
        *(bf16x8*)(Vs + (rr + 32) * LDT + cc) = v1;
        __syncthreads();

        // ---- S = Q K^T (16 rows x 64 cols per wave), 8 MFMAs ----
        f32x4 sf[4];
#pragma unroll
        for (int j = 0; j < 4; ++j)
#pragma unroll
            for (int r = 0; r < 4; ++r) sf[j][r] = 0.f;
#pragma unroll
        for (int t = 0; t < 2; ++t) {
#pragma unroll
            for (int j = 0; j < 4; ++j) {
                bf16x8 kb = *(const bf16x8*)(Ks + (j * 16 + l15) * LDT + t * 32 + quad * 8);
                sf[j] = __builtin_amdgcn_mfma_f32_16x16x32_bf16(qa[t], kb, sf[j], 0, 0, 0);
            }
        }

        // ---- additive mask + row max ----
#pragma unroll
        for (int j = 0; j < 4; ++j)
#pragma unroll
            for (int r = 0; r < 4; ++r)
                sf[j][r] += (float)((j < 2 ? mv0 : mv1)[(j & 1) * 4 + r]);

        float tmax[4];
#pragma unroll
        for (int r = 0; r < 4; ++r)
            tmax[r] = rowmax16(fmaxf(fmaxf(sf[0][r], sf[1][r]), fmaxf(sf[2][r], sf[3][r])));

        float alpha[4], psum[4];
#pragma unroll
        for (int r = 0; r < 4; ++r) {
            const float mn = fmaxf(mrow[r], tmax[r]);
            alpha[r] = EXP2F(mrow[r] - mn);
            mrow[r] = mn;
            psum[r] = 0.f;
        }
#pragma unroll
        for (int j = 0; j < 4; ++j)
#pragma unroll
            for (int r = 0; r < 4; ++r) {
                const float p = EXP2F(sf[j][r] - mrow[r]);
                const bf16 pb = (bf16)p;
                PsW[r * LDP + ((j * 16 + l15) ^ pswz)] = pb;
                psum[r] += (float)pb;
            }
#pragma unroll
        for (int r = 0; r < 4; ++r) {
            psum[r] = rowsum16(psum[r]);
            lrow[r] = lrow[r] * alpha[r] + psum[r];
        }
#pragma unroll
        for (int dj = 0; dj < 4; ++dj)
#pragma unroll
            for (int r = 0; r < 4; ++r) O[dj][r] *= alpha[r];

        // ---- O += P V ----
#pragma unroll
        for (int t = 0; t < 2; ++t) {
            bf16x8 pa = *(const bf16x8*)(PsR + ((t * 32 + quad * 8) ^ rswz));
#pragma unroll
            for (int dj = 0; dj < 4; ++dj) {
                bf16x8 vb = *(const bf16x8*)(Vs + (dj * 16 + l15) * LDT + t * 32 + quad * 8);
                O[dj] = __builtin_amdgcn_mfma_f32_16x16x32_bf16(pa, vb, O[dj], 0, 0, 0);
            }
        }
    }

    float rinv[4];
#pragma unroll
    for (int r = 0; r < 4; ++r) rinv[r] = RCPF(lrow[r]);
#pragma unroll
    for (int dj = 0; dj < 4; ++dj)
#pragma unroll
        for (int r = 0; r < 4; ++r)
            out[((size_t)b * S_ + qt * 64 + w * 16 + quad * 4 + r) * D_
                + h * DK_ + dj * 16 + l15] = (bf16)(O[dj][r] * rinv[r]);
}

// ---------------------------------------------------------------------------
extern "C" void kernel_launch(void* const* d_in, const int* in_sizes, int n_in,
                              void* d_out, int out_size, void* d_ws, size_t ws_size,
                              hipStream_t stream) {
    const float* q    = (const float*)d_in[0];
    const float* k    = (const float*)d_in[1];
    const float* v    = (const float*)d_in[2];
    const int*   mask = (const int*)d_in[3];
    const float* WQw  = (const float*)d_in[4];
    const float* WQb  = (const float*)d_in[5];
    const float* WKw  = (const float*)d_in[6];
    const float* WKb  = (const float*)d_in[7];
    const float* WVw  = (const float*)d_in[8];
    const float* WVb  = (const float*)d_in[9];
    const float* WOw  = (const float*)d_in[10];
    const float* WOb  = (const float*)d_in[11];

    bf16* ws = (bf16*)d_ws;
    bf16* qb  = ws;              // A8  (later aliased by maskp)
    bf16* kb  = qb + A8;         // A8  (later aliased by AO)
    bf16* vb  = kb + A8;         // A8
    bf16* wqb = vb + A8;         // W1 x4
    bf16* wkb = wqb + W1;
    bf16* wvb = wkb + W1;
    bf16* wob = wvb + W1;
    bf16* Qp  = wob + W1;        // [B,H,S,DK]
    bf16* Kp  = Qp + A8;         // [B,H,S,DK]
    bf16* Vp  = Kp + A8;         // [B,H,DK,S] transposed
    bf16* maskp = qb;            // alias: qb dead after Q-GEMM
    bf16* AO    = kb;            // alias: kb dead after K-GEMM

    cvt_all<<<dim3(14336), 256, 0, stream>>>(q, k, v, WQw, WKw, WVw, WOw, ws);

    dim3 gg(M_ / 128, D_ / 128);  // 64 x 8
    gemm_mfma<1><<<gg, 256, 0, stream>>>(qb, wqb, WQb, (void*)Qp, QSCALE);
    gemm_mfma<1><<<gg, 256, 0, stream>>>(kb, wkb, WKb, (void*)Kp, 1.0f);
    gemm_mfma<2><<<gg, 256, 0, stream>>>(vb, wvb, WVb, (void*)Vp, 1.0f);

    mask_cvt<<<dim3(2048), 256, 0, stream>>>(mask, maskp);

    attn_mfma<<<dim3(2048), 256, 0, stream>>>(Qp, Kp, Vp, maskp, AO);

    gemm_mfma<0><<<gg, 256, 0, stream>>>(AO, wob, WOb, d_out, 1.0f);
}